// Round 9
// baseline (756.714 us; speedup 1.0000x reference)
//
#include <hip/hip_runtime.h>

#define NN 100000
#define EE 1600000
#define BB 64
#define NSCAN 98      // ceil(NN/1024)
#define AG6 1024      // grid for F=6 stats
#define AG64 640      // grid for F=64 tiled ata
#define NTILE 1563    // ceil(NN/64)
#define SC_CLS 8                          // dst-space classes (≈ XCDs)
#define SC_REG ((NN + SC_CLS - 1) / SC_CLS)   // 12500 nodes per class
#define SC_GRID 2048                      // blocks; SC_GRID/SC_CLS chunks
#define SC_NCH (SC_GRID / SC_CLS)         // 256 chunks
#define SC_CHSZ ((EE + SC_NCH - 1) / SC_NCH)  // 6250 edges per chunk
#define POOL_BLK 512
#define POOL_WAVES (POOL_BLK * 4)

__device__ __forceinline__ unsigned fmap(float f) {
  unsigned u = __float_as_uint(f);
  return (u & 0x80000000u) ? ~u : (u | 0x80000000u);
}
__device__ __forceinline__ float funmap(unsigned m) {
  unsigned u = (m & 0x80000000u) ? (m ^ 0x80000000u) : ~m;
  return __uint_as_float(u);
}
__device__ __forceinline__ unsigned short f2b(float f) {
  unsigned u = __float_as_uint(f);
  unsigned r = (u + 0x7FFFu + ((u >> 16) & 1u)) >> 16;
  return (unsigned short)r;
}
__device__ __forceinline__ float b2f(unsigned short s) {
  return __uint_as_float(((unsigned)s) << 16);
}

// ---------------- CSR build (by dst) ----------------
__global__ void k_hist(const int* __restrict__ dst, int* __restrict__ counts) {
  int i = blockIdx.x * blockDim.x + threadIdx.x;
  if (i < EE) atomicAdd(&counts[dst[i]], 1);
}

__global__ void k_scan1(const int* __restrict__ counts, int* __restrict__ rowptr,
                        int* __restrict__ partials) {
  __shared__ int buf[1024];
  int i = blockIdx.x * 1024 + threadIdx.x;
  int v = (i < NN) ? counts[i] : 0;
  buf[threadIdx.x] = v;
  __syncthreads();
  for (int off = 1; off < 1024; off <<= 1) {
    int t = (threadIdx.x >= off) ? buf[threadIdx.x - off] : 0;
    __syncthreads();
    buf[threadIdx.x] += t;
    __syncthreads();
  }
  int incl = buf[threadIdx.x];
  if (i < NN) rowptr[i] = incl - v;
  if (threadIdx.x == 1023) partials[blockIdx.x] = incl;
}

__global__ void k_scan2(const int* __restrict__ partials, int* __restrict__ poffs,
                        unsigned* __restrict__ gmax) {
  __shared__ int buf[128];
  int t = threadIdx.x;
  int v = (t < NSCAN) ? partials[t] : 0;
  buf[t] = v;
  __syncthreads();
  for (int off = 1; off < 128; off <<= 1) {
    int u = (t >= off) ? buf[t - off] : 0;
    __syncthreads();
    buf[t] += u;
    __syncthreads();
  }
  poffs[t] = buf[t] - v;
  for (int i = t; i < BB * 64; i += 128) gmax[i] = 0x007FFFFFu;  // fmap(-inf)
}

__global__ void k_scan3(int* __restrict__ rowptr, const int* __restrict__ poffs,
                        int* __restrict__ cursor) {
  int i = blockIdx.x * 1024 + threadIdx.x;
  if (i < NN) {
    int val = rowptr[i] + poffs[blockIdx.x];
    rowptr[i] = val;
    cursor[i] = val;
  }
  if (i == 0) rowptr[NN] = EE;
}

// spatially-partitioned scatter: block b handles dst-class (b&7) over chunk (b>>3).
__global__ __launch_bounds__(256) void k_scatter(const int* __restrict__ src,
                                                 const int* __restrict__ dst,
                                                 int* __restrict__ cursor,
                                                 int* __restrict__ adjsrc) {
  int cls = blockIdx.x & (SC_CLS - 1);
  int chunk = blockIdx.x >> 3;
  int lo = cls * SC_REG;
  int hi = min(lo + SC_REG, NN);
  int base = chunk * SC_CHSZ;
  int end = min(base + SC_CHSZ, EE);
  for (int i = base + threadIdx.x; i < end; i += 256) {
    int d = dst[i];
    if (d >= lo && d < hi) {
      int pos = atomicAdd(&cursor[d], 1);
      adjsrc[pos] = src[i];
    }
  }
}

// ---------------- layer-0 aggregation: f32 gather, F=6 ----------------
__global__ __launch_bounds__(256) void k_agg0(const float* __restrict__ xin,
                                              const int* __restrict__ rowptr,
                                              const int* __restrict__ adjsrc,
                                              float* __restrict__ out) {
  int w = __builtin_amdgcn_readfirstlane(threadIdx.x >> 6);
  int lane = threadIdx.x & 63;
  int wid = blockIdx.x * 4 + w;
  if (wid >= NN) return;
  int s = rowptr[wid], e = rowptr[wid + 1];
  bool act = lane < 6;
  float den = 0.f, num = 0.f;
  int i = s;
  for (; i + 3 < e; i += 4) {
    int n0 = adjsrc[i], n1 = adjsrc[i + 1], n2 = adjsrc[i + 2], n3 = adjsrc[i + 3];
    float v0 = act ? xin[(size_t)n0 * 6 + lane] : 0.f;
    float v1 = act ? xin[(size_t)n1 * 6 + lane] : 0.f;
    float v2 = act ? xin[(size_t)n2 * 6 + lane] : 0.f;
    float v3 = act ? xin[(size_t)n3 * 6 + lane] : 0.f;
    float m0 = fminf(fmaxf(v0, 0.f) + 1e-7f, 80.f);
    float m1 = fminf(fmaxf(v1, 0.f) + 1e-7f, 80.f);
    float m2 = fminf(fmaxf(v2, 0.f) + 1e-7f, 80.f);
    float m3 = fminf(fmaxf(v3, 0.f) + 1e-7f, 80.f);
    float e0 = __expf(m0), e1 = __expf(m1), e2 = __expf(m2), e3 = __expf(m3);
    den += (e0 + e1) + (e2 + e3);
    num += (m0 * e0 + m1 * e1) + (m2 * e2 + m3 * e3);
  }
  for (; i < e; ++i) {
    int n0 = adjsrc[i];
    float v0 = act ? xin[(size_t)n0 * 6 + lane] : 0.f;
    float m0 = fminf(fmaxf(v0, 0.f) + 1e-7f, 80.f);
    float e0 = __expf(m0);
    den += e0;
    num += m0 * e0;
  }
  if (act) {
    float xr = xin[(size_t)wid * 6 + lane];
    out[(size_t)wid * 6 + lane] = num / (den + 1e-16f) + xr;
  }
}

// ---------------- layers 1-3 aggregation: dual-edge ushort2 bf16 gather ----------
// Lanes 0-31 cover all 64 channels (2/lane) of even-slot edges; lanes 32-63 the
// odd-slot edges. One gather instruction fetches TWO full xb rows (256B).
__global__ __launch_bounds__(256) void k_aggb(const unsigned* __restrict__ xb2,
                                              const float* __restrict__ h,
                                              const int* __restrict__ rowptr,
                                              const int* __restrict__ adjsrc,
                                              float* __restrict__ out) {
  int w = __builtin_amdgcn_readfirstlane(threadIdx.x >> 6);
  int wid = blockIdx.x * 4 + w;
  if (wid >= NN) return;
  int lane = threadIdx.x & 63;
  int half = lane >> 5;   // 0: even edge slots, 1: odd edge slots
  int cl = lane & 31;     // channel pair -> channels 2cl, 2cl+1
  int s = rowptr[wid], e = rowptr[wid + 1];
  float den0 = 0.f, den1 = 0.f, num0 = 0.f, num1 = 0.f;
  int i = s;
  for (; i + 15 < e; i += 16) {              // 16 edges in flight per wave
    int n[8];
#pragma unroll
    for (int k = 0; k < 8; ++k) n[k] = adjsrc[i + 2 * k + half];
    unsigned u[8];
#pragma unroll
    for (int k = 0; k < 8; ++k) u[k] = xb2[(size_t)n[k] * 32 + cl];
#pragma unroll
    for (int k = 0; k < 8; ++k) {
      float v0 = b2f((unsigned short)(u[k] & 0xffff));
      float v1 = b2f((unsigned short)(u[k] >> 16));
      float m0 = fminf(v0 + 1e-7f, 80.f);    // xb already relu'd
      float m1 = fminf(v1 + 1e-7f, 80.f);
      float e0 = __expf(m0), e1 = __expf(m1);
      den0 += e0; num0 += m0 * e0;
      den1 += e1; num1 += m1 * e1;
    }
  }
  for (; i < e; i += 2) {                    // 2-edge tail with masking
    int ei = i + half;
    bool valid = ei < e;
    int n0 = valid ? adjsrc[ei] : adjsrc[s];
    unsigned u = xb2[(size_t)n0 * 32 + cl];
    float v0 = b2f((unsigned short)(u & 0xffff));
    float v1 = b2f((unsigned short)(u >> 16));
    float m0 = fminf(v0 + 1e-7f, 80.f);
    float m1 = fminf(v1 + 1e-7f, 80.f);
    float e0 = valid ? __expf(m0) : 0.f;
    float e1 = valid ? __expf(m1) : 0.f;
    den0 += e0; num0 += m0 * e0;
    den1 += e1; num1 += m1 * e1;
  }
  // merge even/odd halves (pure sums -> additive)
  den0 += __shfl_xor(den0, 32, 64);
  den1 += __shfl_xor(den1, 32, 64);
  num0 += __shfl_xor(num0, 32, 64);
  num1 += __shfl_xor(num1, 32, 64);
  if (half == 0) {
    const float2 hres = *(const float2*)&h[(size_t)wid * 64 + 2 * cl];
    float2 o;
    o.x = num0 / (den0 + 1e-16f) + fmaxf(hres.x, 0.f);
    o.y = num1 / (den1 + 1e-16f) + fmaxf(hres.y, 0.f);
    *(float2*)&out[(size_t)wid * 64 + 2 * cl] = o;
  }
}

// ---------------- F=6 stats: shfl outer product (cheap) ----------------
__global__ __launch_bounds__(256) void k_ata6(const float* __restrict__ A,
                                              float* __restrict__ part) {
  constexpr int F = 6;
  int lane = threadIdx.x & 63;
  int w = __builtin_amdgcn_readfirstlane(threadIdx.x >> 6);
  bool act = lane < F;
  float Sloc[F];
#pragma unroll
  for (int c = 0; c < F; ++c) Sloc[c] = 0.f;
  float csloc = 0.f;
  int NW = gridDim.x * 4;
  for (int node = blockIdx.x * 4 + w; node < NN; node += NW) {
    float a = act ? A[(size_t)node * F + lane] : 0.f;
    csloc += a;
#pragma unroll
    for (int c = 0; c < F; ++c) {
      float ac = __shfl(a, c, 64);
      Sloc[c] += ac * a;
    }
  }
  __shared__ float ls[F * F + F];
  for (int idx = threadIdx.x; idx < F * F + F; idx += 256) ls[idx] = 0.f;
  __syncthreads();
  if (act) {
#pragma unroll
    for (int c = 0; c < F; ++c) atomicAdd(&ls[c * F + lane], Sloc[c]);
    atomicAdd(&ls[F * F + lane], csloc);
  }
  __syncthreads();
  float* dstp = part + (size_t)blockIdx.x * (F * F + F);
  for (int idx = threadIdx.x; idx < F * F + F; idx += 256) dstp[idx] = ls[idx];
}

// ---------------- F=64 stats: LDS-tiled rank-1 accumulation ----------------
__global__ __launch_bounds__(256) void k_ata64(const float* __restrict__ A,
                                               float* __restrict__ part) {
  __shared__ float lA[64 * 64];   // [node][ch]
  __shared__ float lcs[64];
  int tid = threadIdx.x;
  int tx = tid & 15, ty = tid >> 4;
  float acc[4][4];
#pragma unroll
  for (int i = 0; i < 4; ++i)
#pragma unroll
    for (int j = 0; j < 4; ++j) acc[i][j] = 0.f;
  float cs0 = 0.f, cs1 = 0.f, cs2 = 0.f, cs3 = 0.f;
  if (tid < 64) lcs[tid] = 0.f;
  const float4* A4 = (const float4*)A;
  for (int tile = blockIdx.x; tile < NTILE; tile += gridDim.x) {
    int nbase = tile * 64;
    __syncthreads();   // protect lA from previous iteration's readers
#pragma unroll
    for (int k = 0; k < 4; ++k) {
      int node = ty + k * 16;
      int gn = nbase + node;
      float4 v = (gn < NN) ? A4[(size_t)gn * 16 + tx]
                           : make_float4(0.f, 0.f, 0.f, 0.f);
      *(float4*)&lA[node * 64 + tx * 4] = v;
      cs0 += v.x; cs1 += v.y; cs2 += v.z; cs3 += v.w;
    }
    __syncthreads();
#pragma unroll 4
    for (int node = 0; node < 64; ++node) {
      float4 rv = *(const float4*)&lA[node * 64 + ty * 4];
      float4 cv = *(const float4*)&lA[node * 64 + tx * 4];
      acc[0][0] += rv.x * cv.x; acc[0][1] += rv.x * cv.y;
      acc[0][2] += rv.x * cv.z; acc[0][3] += rv.x * cv.w;
      acc[1][0] += rv.y * cv.x; acc[1][1] += rv.y * cv.y;
      acc[1][2] += rv.y * cv.z; acc[1][3] += rv.y * cv.w;
      acc[2][0] += rv.z * cv.x; acc[2][1] += rv.z * cv.y;
      acc[2][2] += rv.z * cv.z; acc[2][3] += rv.z * cv.w;
      acc[3][0] += rv.w * cv.x; acc[3][1] += rv.w * cv.y;
      acc[3][2] += rv.w * cv.z; acc[3][3] += rv.w * cv.w;
    }
  }
  __syncthreads();
  atomicAdd(&lcs[tx * 4 + 0], cs0);
  atomicAdd(&lcs[tx * 4 + 1], cs1);
  atomicAdd(&lcs[tx * 4 + 2], cs2);
  atomicAdd(&lcs[tx * 4 + 3], cs3);
  float* dstp = part + (size_t)blockIdx.x * 4160;
#pragma unroll
  for (int i = 0; i < 4; ++i)
#pragma unroll
    for (int j = 0; j < 4; ++j)
      dstp[(ty * 4 + i) * 64 + tx * 4 + j] = acc[i][j];
  __syncthreads();
  if (tid < 64) dstp[4096 + tid] = lcs[tid];
}

// ---------------- reduce partials: block-per-index tree ----------------
__global__ void k_redB(const float* __restrict__ part, float* __restrict__ out,
                       int stride, int ngrid) {
  __shared__ float buf[256];
  int i = blockIdx.x;
  float s = 0.f;
  for (int g = threadIdx.x; g < ngrid; g += 256) s += part[(size_t)g * stride + i];
  buf[threadIdx.x] = s;
  __syncthreads();
  for (int off = 128; off; off >>= 1) {
    if (threadIdx.x < off) buf[threadIdx.x] += buf[threadIdx.x + off];
    __syncthreads();
  }
  if (threadIdx.x == 0) out[i] = buf[0];
}

// ---------------- BN params from covariance ----------------
template<int FIN, int FMID>
__global__ void k_bnprep(const float* __restrict__ S, const float* __restrict__ cs,
                         const float* __restrict__ Wm, const float* __restrict__ bm,
                         const float* __restrict__ gamma, const float* __restrict__ beta,
                         float* __restrict__ ab) {
  int j = blockIdx.x;
  int lane = threadIdx.x;
  bool act = (FIN == 64) || (lane < FIN);
  float wj = act ? Wm[lane * FMID + j] : 0.f;
  float mb = act ? cs[lane] * (1.f / NN) : 0.f;
  float t = mb * wj;
#pragma unroll
  for (int off = 32; off; off >>= 1) t += __shfl_xor(t, off, 64);
  float mulin = t;
  float acc = 0.f;
  for (int c = 0; c < FIN; ++c) {
    float sv = act ? S[c * FIN + lane] : 0.f;
    float p = sv * wj;
#pragma unroll
    for (int off = 32; off; off >>= 1) p += __shfl_xor(p, off, 64);
    acc += p * __shfl(wj, c, 64);
  }
  if (lane == 0) {
    float var = acc * (1.f / NN) - mulin * mulin;
    float rstd = rsqrtf(fmaxf(var, 0.f) + 1e-5f);
    float sc = rstd * gamma[j];
    ab[j] = sc;
    ab[FMID + j] = beta[j] - mulin * sc;
  }
}

// ---------------- fused GEMM1 + BN + relu + GEMM2 + residual (+ bf16 relu copy) ----
// FMID==128: mid activations stored as packed bf16 pairs -> LDS 33.3KB, 4 blocks/CU.
template<int FIN, int FMID, int FOUT, int MODE>  // MODE 0: H=relu(out); 1: H+=out
__global__ __launch_bounds__(256) void k_layer(const float* __restrict__ A,
                                               const float* __restrict__ Wm,
                                               const float* __restrict__ ab,
                                               const float* __restrict__ W2,
                                               const float* __restrict__ b2,
                                               float* __restrict__ H,
                                               unsigned short* __restrict__ XB) {
  constexpr bool PK = (FMID == 128);
  constexpr int SM = FMID + 1;
  constexpr int MW = FMID / 4;
  constexpr int OW = FOUT / 4;
  __shared__ float lA[FIN * 65];             // transposed: lA[c][node], stride 65
  __shared__ unsigned lHp[PK ? 64 * 65 : 1]; // packed bf16 pairs [node][pair], stride 65
  __shared__ float lH[PK ? 1 : 64 * SM];
  int tid = threadIdx.x;
  int lane = tid & 63;
  int w = __builtin_amdgcn_readfirstlane(tid >> 6);
  int nbase = blockIdx.x * 64;
  if (FIN == 64) {
    const float4* A4 = (const float4*)A;
    for (int e = tid; e < 64 * 16; e += 256) {
      int node = e >> 4;
      int c4 = (e & 15) << 2;
      int gn = nbase + node;
      float4 v = (gn < NN) ? A4[(size_t)gn * 16 + (e & 15)] : make_float4(0.f, 0.f, 0.f, 0.f);
      lA[(c4 + 0) * 65 + node] = v.x;
      lA[(c4 + 1) * 65 + node] = v.y;
      lA[(c4 + 2) * 65 + node] = v.z;
      lA[(c4 + 3) * 65 + node] = v.w;
    }
  } else {
    for (int e = tid; e < 64 * FIN; e += 256) {
      int node = e / FIN, c = e - node * FIN;
      int gn = nbase + node;
      lA[c * 65 + node] = (gn < NN) ? A[(size_t)gn * FIN + c] : 0.f;
    }
  }
  __syncthreads();
  // phase 1: mid = A @ Wm (this wave's MW channels) + BN affine + relu -> LDS
  float acc[MW];
#pragma unroll
  for (int j = 0; j < MW; ++j) acc[j] = 0.f;
#pragma unroll 4
  for (int c = 0; c < FIN; ++c) {
    float a = lA[c * 65 + lane];
#pragma unroll
    for (int j = 0; j < MW; ++j) acc[j] += a * Wm[c * FMID + w * MW + j];
  }
  if constexpr (PK) {
#pragma unroll
    for (int j = 0; j < MW; j += 2) {
      float v0 = fmaxf(acc[j] * ab[w * MW + j] + ab[FMID + w * MW + j], 0.f);
      float v1 = fmaxf(acc[j + 1] * ab[w * MW + j + 1] + ab[FMID + w * MW + j + 1], 0.f);
      lHp[lane * 65 + (w * MW + j) / 2] =
          (unsigned)f2b(v0) | ((unsigned)f2b(v1) << 16);
    }
  } else {
#pragma unroll
    for (int j = 0; j < MW; ++j) {
      float sc = ab[w * MW + j];
      float sh = ab[FMID + w * MW + j];
      lH[lane * SM + w * MW + j] = fmaxf(acc[j] * sc + sh, 0.f);
    }
  }
  __syncthreads();
  // phase 2: out = h1 @ W2 + b2 (this wave's OW channels)
  float acc2[OW];
#pragma unroll
  for (int j = 0; j < OW; ++j) acc2[j] = b2[w * OW + j];
  if constexpr (PK) {
#pragma unroll 4
    for (int c2 = 0; c2 < FMID / 2; ++c2) {
      unsigned u = lHp[lane * 65 + c2];
      float lo = b2f((unsigned short)(u & 0xffff));
      float hi = b2f((unsigned short)(u >> 16));
#pragma unroll
      for (int j = 0; j < OW; ++j) {
        acc2[j] += lo * W2[(2 * c2) * FOUT + w * OW + j];
        acc2[j] += hi * W2[(2 * c2 + 1) * FOUT + w * OW + j];
      }
    }
  } else {
#pragma unroll 4
    for (int c = 0; c < FMID; ++c) {
      float hv = lH[lane * SM + c];
#pragma unroll
      for (int j = 0; j < OW; ++j) acc2[j] += hv * W2[c * FOUT + w * OW + j];
    }
  }
  int node = nbase + lane;
  if (node < NN) {
    size_t base = (size_t)node * FOUT + w * OW;
    if (MODE == 0) {
#pragma unroll
      for (int j = 0; j < OW; ++j) {
        float hn = fmaxf(acc2[j], 0.f);
        H[base + j] = hn;
        XB[base + j] = f2b(hn);           // already >= 0
      }
    } else {
#pragma unroll
      for (int j = 0; j < OW; ++j) {
        float hn = H[base + j] + acc2[j];
        H[base + j] = hn;
        XB[base + j] = f2b(fmaxf(hn, 0.f));
      }
    }
  }
}

// ---------------- pool: segmented register max (batch is sorted) ----------------
__global__ __launch_bounds__(256) void k_pool(const float* __restrict__ h,
                                              const int* __restrict__ batch,
                                              unsigned* __restrict__ gmax) {
  int wgid = blockIdx.x * 4 + (threadIdx.x >> 6);
  int lane = threadIdx.x & 63;
  const int per = (NN + POOL_WAVES - 1) / POOL_WAVES;  // 49
  int n0 = wgid * per;
  int n1 = min(n0 + per, NN);
  if (n0 >= NN) return;
  int g = batch[n0];
  float m = -INFINITY;
  for (int node = n0; node < n1; ++node) {
    int b = batch[node];
    if (b != g) {
      atomicMax(&gmax[(g << 6) + lane], fmap(m));
      m = -INFINITY;
      g = b;
    }
    m = fmaxf(m, h[(size_t)node * 64 + lane]);
  }
  atomicMax(&gmax[(g << 6) + lane], fmap(m));
}

__global__ void k_final(const unsigned* __restrict__ gmax, const float* __restrict__ w1,
                        const float* __restrict__ b1, const float* __restrict__ w2,
                        const float* __restrict__ b2, float* __restrict__ out) {
  int b = blockIdx.x;
  __shared__ float g[64], hid[64];
  int t = threadIdx.x;
  if (t < 64) {
    float v = funmap(gmax[b * 64 + t]);
    if (v == -INFINITY) v = 0.f;
    g[t] = v;
  }
  __syncthreads();
  if (t < 64) {
    float acc = b1[t];
    for (int c = 0; c < 64; ++c) acc += g[c] * w1[c * 64 + t];
    hid[t] = fmaxf(acc, 0.f);
  }
  __syncthreads();
  if (t < 80) {
    float acc = b2[t];
    for (int c = 0; c < 64; ++c) acc += hid[c] * w2[c * 80 + t];
    out[b * 80 + t] = acc;
  }
}

extern "C" void kernel_launch(void* const* d_in, const int* in_sizes, int n_in,
                              void* d_out, int out_size, void* d_ws, size_t ws_size,
                              hipStream_t stream) {
  const float* x       = (const float*)d_in[0];
  const int*   ei      = (const int*)d_in[1];
  const int*   batch   = (const int*)d_in[2];
  const float* cin_w1  = (const float*)d_in[3];
  const float* cin_b1  = (const float*)d_in[4];
  const float* cin_g1  = (const float*)d_in[5];
  const float* cin_be1 = (const float*)d_in[6];
  const float* cin_w2  = (const float*)d_in[7];
  const float* cin_b2  = (const float*)d_in[8];
  const float* L_w1    = (const float*)d_in[9];
  const float* L_b1    = (const float*)d_in[10];
  const float* L_g1    = (const float*)d_in[11];
  const float* L_be1   = (const float*)d_in[12];
  const float* L_w2    = (const float*)d_in[13];
  const float* L_b2    = (const float*)d_in[14];
  const float* mlp_w1  = (const float*)d_in[15];
  const float* mlp_b1  = (const float*)d_in[16];
  const float* mlp_w2  = (const float*)d_in[17];
  const float* mlp_b2  = (const float*)d_in[18];

  char* ws = (char*)d_ws;
  size_t off = 0;
  auto alloc = [&](size_t bytes) -> void* {
    void* p = ws + off;
    off = (off + bytes + 255) & ~(size_t)255;
    return p;
  };
  float*          A       = (float*)alloc((size_t)NN * 64 * 4);
  float*          h       = (float*)alloc((size_t)NN * 64 * 4);
  unsigned short* xb      = (unsigned short*)alloc((size_t)NN * 64 * 2);
  int*            rowptr  = (int*)alloc((size_t)(NN + 1) * 4);
  int*            cursor  = (int*)alloc((size_t)NN * 4);
  int*            adjsrc  = (int*)alloc((size_t)EE * 4);
  int*            partial = (int*)alloc(NSCAN * 4);
  int*            poffs   = (int*)alloc(128 * 4);
  float*          part    = (float*)alloc((size_t)AG6 * 4160 * 4);  // fits both uses
  float*          Sfin    = (float*)alloc((size_t)4 * 4160 * 4);
  float*          ab      = (float*)alloc((size_t)4 * 256 * 4);
  unsigned*       gmax    = (unsigned*)alloc((size_t)BB * 64 * 4);
  (void)ws_size; (void)in_sizes; (void)n_in; (void)out_size;

  const int* srcp = ei;
  const int* dstp = ei + EE;

  // CSR build
  hipMemsetAsync(cursor, 0, (size_t)NN * 4, stream);
  k_hist<<<(EE + 255) / 256, 256, 0, stream>>>(dstp, cursor);
  k_scan1<<<NSCAN, 1024, 0, stream>>>(cursor, rowptr, partial);
  k_scan2<<<1, 128, 0, stream>>>(partial, poffs, gmax);
  k_scan3<<<NSCAN, 1024, 0, stream>>>(rowptr, poffs, cursor);
  k_scatter<<<SC_GRID, 256, 0, stream>>>(srcp, dstp, cursor, adjsrc);

  const int NB64 = (NN + 63) / 64;  // 1563

  // Layer 0: x[N,6] -> h[N,64] (+ xb = bf16 relu copy)
  {
    float* S = Sfin;
    float* cs = S + 6 * 6;
    float* ab0 = ab;
    k_agg0<<<NN / 4, 256, 0, stream>>>(x, rowptr, adjsrc, A);
    k_ata6<<<AG6, 256, 0, stream>>>(A, part);
    k_redB<<<42, 256, 0, stream>>>(part, S, 42, AG6);
    k_bnprep<6, 12><<<12, 64, 0, stream>>>(S, cs, cin_w1, cin_b1, cin_g1, cin_be1, ab0);
    k_layer<6, 12, 64, 0><<<NB64, 256, 0, stream>>>(A, cin_w1, ab0, cin_w2, cin_b2, h, xb);
  }

  // Layers 1..3: h += MLP(BN(agg(relu(h)) @ W1)) @ W2
  for (int i = 0; i < 3; ++i) {
    float* S = Sfin + (size_t)(i + 1) * 4160;
    float* cs = S + 64 * 64;
    float* abi = ab + (size_t)(i + 1) * 256;
    k_aggb<<<NN / 4, 256, 0, stream>>>((const unsigned*)xb, h, rowptr, adjsrc, A);
    k_ata64<<<AG64, 256, 0, stream>>>(A, part);
    k_redB<<<4160, 256, 0, stream>>>(part, S, 4160, AG64);
    k_bnprep<64, 128><<<128, 64, 0, stream>>>(S, cs, L_w1 + (size_t)i * 64 * 128,
                                              L_b1 + i * 128, L_g1 + i * 128,
                                              L_be1 + i * 128, abi);
    k_layer<64, 128, 64, 1><<<NB64, 256, 0, stream>>>(A, L_w1 + (size_t)i * 64 * 128, abi,
                                                      L_w2 + (size_t)i * 128 * 64,
                                                      L_b2 + i * 64, h, xb);
  }

  // Global max pool + final MLP
  k_pool<<<POOL_BLK, 256, 0, stream>>>(h, batch, gmax);
  k_final<<<BB, 128, 0, stream>>>(gmax, mlp_w1, mlp_b1, mlp_w2, mlp_b2, (float*)d_out);
}

// Round 10
// 747.728 us; speedup vs baseline: 1.0120x; 1.0120x over previous
//
#include <hip/hip_runtime.h>

#define NN 100000
#define EE 1600000
#define BB 64
#define NSCAN 98      // ceil(NN/1024)
#define AG6 1024      // grid for F=6 stats
#define AG64 640      // grid for F=64 tiled ata
#define NTILE 1563    // ceil(NN/64)
#define SC_CLS 8                          // dst-space buckets (≈ XCDs)
#define SC_REG ((NN + SC_CLS - 1) / SC_CLS)   // 12500 nodes per bucket
#define SC_GRID 2048                      // phase-B blocks
#define SC_NCH (SC_GRID / SC_CLS)         // 256 chunks per bucket
#define BK_GRID 512                       // phase-A blocks
#define BK_CH ((EE + BK_GRID - 1) / BK_GRID)  // 3125 edges per block
#define POOL_BLK 512
#define POOL_WAVES (POOL_BLK * 4)

__device__ __forceinline__ unsigned fmap(float f) {
  unsigned u = __float_as_uint(f);
  return (u & 0x80000000u) ? ~u : (u | 0x80000000u);
}
__device__ __forceinline__ float funmap(unsigned m) {
  unsigned u = (m & 0x80000000u) ? (m ^ 0x80000000u) : ~m;
  return __uint_as_float(u);
}
__device__ __forceinline__ unsigned short f2b(float f) {
  unsigned u = __float_as_uint(f);
  unsigned r = (u + 0x7FFFu + ((u >> 16) & 1u)) >> 16;
  return (unsigned short)r;
}
__device__ __forceinline__ float b2f(unsigned short s) {
  return __uint_as_float(((unsigned)s) << 16);
}

// ---------------- CSR build (by dst) ----------------
__global__ void k_hist(const int* __restrict__ dst, int* __restrict__ counts) {
  int i = blockIdx.x * blockDim.x + threadIdx.x;
  if (i < EE) atomicAdd(&counts[dst[i]], 1);
}

__global__ void k_scan1(const int* __restrict__ counts, int* __restrict__ rowptr,
                        int* __restrict__ partials) {
  __shared__ int buf[1024];
  int i = blockIdx.x * 1024 + threadIdx.x;
  int v = (i < NN) ? counts[i] : 0;
  buf[threadIdx.x] = v;
  __syncthreads();
  for (int off = 1; off < 1024; off <<= 1) {
    int t = (threadIdx.x >= off) ? buf[threadIdx.x - off] : 0;
    __syncthreads();
    buf[threadIdx.x] += t;
    __syncthreads();
  }
  int incl = buf[threadIdx.x];
  if (i < NN) rowptr[i] = incl - v;
  if (threadIdx.x == 1023) partials[blockIdx.x] = incl;
}

__global__ void k_scan2(const int* __restrict__ partials, int* __restrict__ poffs,
                        unsigned* __restrict__ gmax) {
  __shared__ int buf[128];
  int t = threadIdx.x;
  int v = (t < NSCAN) ? partials[t] : 0;
  buf[t] = v;
  __syncthreads();
  for (int off = 1; off < 128; off <<= 1) {
    int u = (t >= off) ? buf[t - off] : 0;
    __syncthreads();
    buf[t] += u;
    __syncthreads();
  }
  poffs[t] = buf[t] - v;
  for (int i = t; i < BB * 64; i += 128) gmax[i] = 0x007FFFFFu;  // fmap(-inf)
}

__global__ void k_scan3(int* __restrict__ rowptr, const int* __restrict__ poffs,
                        int* __restrict__ cursor, int* __restrict__ bcur) {
  int i = blockIdx.x * 1024 + threadIdx.x;
  if (i < NN) {
    int val = rowptr[i] + poffs[blockIdx.x];
    rowptr[i] = val;
    cursor[i] = val;
    if (i % SC_REG == 0) bcur[i / SC_REG] = val;  // bucket write cursors
  }
  if (i == 0) rowptr[NN] = EE;
}

// phase A: partition edges into 8 dst-range buckets as (src,dst) pairs.
// Per-(block,bucket) runs are contiguous -> full-line writebacks.
__global__ __launch_bounds__(256) void k_bucket(const int* __restrict__ src,
                                                const int* __restrict__ dst,
                                                int* __restrict__ bcur,
                                                int2* __restrict__ ebuf) {
  __shared__ int lcnt[SC_CLS], lbase[SC_CLS];
  int tid = threadIdx.x;
  if (tid < SC_CLS) lcnt[tid] = 0;
  __syncthreads();
  int base = blockIdx.x * BK_CH;
  int end = min(base + BK_CH, EE);
  int s[13], d[13], nb = 0;
  for (int i = base + tid; i < end; i += 256) {
    s[nb] = src[i];
    d[nb] = dst[i];
    ++nb;
  }
  int pc[SC_CLS];
#pragma unroll
  for (int b = 0; b < SC_CLS; ++b) pc[b] = 0;
  for (int k = 0; k < nb; ++k) pc[d[k] / SC_REG]++;
#pragma unroll
  for (int b = 0; b < SC_CLS; ++b)
    if (pc[b]) atomicAdd(&lcnt[b], pc[b]);
  __syncthreads();
  if (tid < SC_CLS) {
    lbase[tid] = atomicAdd(&bcur[tid], lcnt[tid]);
    lcnt[tid] = 0;
  }
  __syncthreads();
  for (int k = 0; k < nb; ++k) {
    int b = d[k] / SC_REG;
    int pos = lbase[b] + atomicAdd(&lcnt[b], 1);
    ebuf[pos] = make_int2(s[k], d[k]);
  }
}

// phase B: class c (blockIdx&7 -> one XCD) scatters only bucket c.
// Streaming reads (1.6MB) + dirty region (850KB) both fit the 4MB XCD L2.
__global__ __launch_bounds__(256) void k_scatter2(const int2* __restrict__ ebuf,
                                                  const int* __restrict__ rowptr,
                                                  int* __restrict__ cursor,
                                                  int* __restrict__ adjsrc) {
  int cls = blockIdx.x & (SC_CLS - 1);
  int chunk = blockIdx.x >> 3;
  int lo = rowptr[cls * SC_REG];
  int hi = rowptr[min((cls + 1) * SC_REG, NN)];
  int n = hi - lo;
  int chsz = (n + SC_NCH - 1) / SC_NCH;
  int b0 = lo + chunk * chsz;
  int b1 = min(b0 + chsz, hi);
  for (int i = b0 + threadIdx.x; i < b1; i += 256) {
    int2 e = ebuf[i];
    int pos = atomicAdd(&cursor[e.y], 1);
    adjsrc[pos] = e.x;
  }
}

// ---------------- layer-0 aggregation: f32 gather, F=6 ----------------
__global__ __launch_bounds__(256) void k_agg0(const float* __restrict__ xin,
                                              const int* __restrict__ rowptr,
                                              const int* __restrict__ adjsrc,
                                              float* __restrict__ out) {
  int w = __builtin_amdgcn_readfirstlane(threadIdx.x >> 6);
  int lane = threadIdx.x & 63;
  int wid = blockIdx.x * 4 + w;
  if (wid >= NN) return;
  int s = rowptr[wid], e = rowptr[wid + 1];
  bool act = lane < 6;
  float den = 0.f, num = 0.f;
  int i = s;
  for (; i + 3 < e; i += 4) {
    int n0 = adjsrc[i], n1 = adjsrc[i + 1], n2 = adjsrc[i + 2], n3 = adjsrc[i + 3];
    float v0 = act ? xin[(size_t)n0 * 6 + lane] : 0.f;
    float v1 = act ? xin[(size_t)n1 * 6 + lane] : 0.f;
    float v2 = act ? xin[(size_t)n2 * 6 + lane] : 0.f;
    float v3 = act ? xin[(size_t)n3 * 6 + lane] : 0.f;
    float m0 = fminf(fmaxf(v0, 0.f) + 1e-7f, 80.f);
    float m1 = fminf(fmaxf(v1, 0.f) + 1e-7f, 80.f);
    float m2 = fminf(fmaxf(v2, 0.f) + 1e-7f, 80.f);
    float m3 = fminf(fmaxf(v3, 0.f) + 1e-7f, 80.f);
    float e0 = __expf(m0), e1 = __expf(m1), e2 = __expf(m2), e3 = __expf(m3);
    den += (e0 + e1) + (e2 + e3);
    num += (m0 * e0 + m1 * e1) + (m2 * e2 + m3 * e3);
  }
  for (; i < e; ++i) {
    int n0 = adjsrc[i];
    float v0 = act ? xin[(size_t)n0 * 6 + lane] : 0.f;
    float m0 = fminf(fmaxf(v0, 0.f) + 1e-7f, 80.f);
    float e0 = __expf(m0);
    den += e0;
    num += m0 * e0;
  }
  if (act) {
    float xr = xin[(size_t)wid * 6 + lane];
    out[(size_t)wid * 6 + lane] = num / (den + 1e-16f) + xr;
  }
}

// ---------------- layers 1-3 aggregation: bf16 gather, f32 residual ----------------
__global__ __launch_bounds__(256) void k_aggb(const unsigned short* __restrict__ xb,
                                              const float* __restrict__ h,
                                              const int* __restrict__ rowptr,
                                              const int* __restrict__ adjsrc,
                                              float* __restrict__ out) {
  int w = __builtin_amdgcn_readfirstlane(threadIdx.x >> 6);
  int lane = threadIdx.x & 63;
  int wid = blockIdx.x * 4 + w;
  if (wid >= NN) return;
  int s = rowptr[wid], e = rowptr[wid + 1];
  float den = 0.f, num = 0.f;
  int i = s;
  for (; i + 3 < e; i += 4) {
    int n0 = adjsrc[i], n1 = adjsrc[i + 1], n2 = adjsrc[i + 2], n3 = adjsrc[i + 3];
    float v0 = b2f(xb[(size_t)n0 * 64 + lane]);
    float v1 = b2f(xb[(size_t)n1 * 64 + lane]);
    float v2 = b2f(xb[(size_t)n2 * 64 + lane]);
    float v3 = b2f(xb[(size_t)n3 * 64 + lane]);
    float m0 = fminf(v0 + 1e-7f, 80.f);   // xb already relu'd
    float m1 = fminf(v1 + 1e-7f, 80.f);
    float m2 = fminf(v2 + 1e-7f, 80.f);
    float m3 = fminf(v3 + 1e-7f, 80.f);
    float e0 = __expf(m0), e1 = __expf(m1), e2 = __expf(m2), e3 = __expf(m3);
    den += (e0 + e1) + (e2 + e3);
    num += (m0 * e0 + m1 * e1) + (m2 * e2 + m3 * e3);
  }
  for (; i < e; ++i) {
    int n0 = adjsrc[i];
    float v0 = b2f(xb[(size_t)n0 * 64 + lane]);
    float m0 = fminf(v0 + 1e-7f, 80.f);
    float e0 = __expf(m0);
    den += e0;
    num += m0 * e0;
  }
  float res = fmaxf(h[(size_t)wid * 64 + lane], 0.f);
  out[(size_t)wid * 64 + lane] = num / (den + 1e-16f) + res;
}

// ---------------- F=6 stats: shfl outer product (cheap) ----------------
__global__ __launch_bounds__(256) void k_ata6(const float* __restrict__ A,
                                              float* __restrict__ part) {
  constexpr int F = 6;
  int lane = threadIdx.x & 63;
  int w = __builtin_amdgcn_readfirstlane(threadIdx.x >> 6);
  bool act = lane < F;
  float Sloc[F];
#pragma unroll
  for (int c = 0; c < F; ++c) Sloc[c] = 0.f;
  float csloc = 0.f;
  int NW = gridDim.x * 4;
  for (int node = blockIdx.x * 4 + w; node < NN; node += NW) {
    float a = act ? A[(size_t)node * F + lane] : 0.f;
    csloc += a;
#pragma unroll
    for (int c = 0; c < F; ++c) {
      float ac = __shfl(a, c, 64);
      Sloc[c] += ac * a;
    }
  }
  __shared__ float ls[F * F + F];
  for (int idx = threadIdx.x; idx < F * F + F; idx += 256) ls[idx] = 0.f;
  __syncthreads();
  if (act) {
#pragma unroll
    for (int c = 0; c < F; ++c) atomicAdd(&ls[c * F + lane], Sloc[c]);
    atomicAdd(&ls[F * F + lane], csloc);
  }
  __syncthreads();
  float* dstp = part + (size_t)blockIdx.x * (F * F + F);
  for (int idx = threadIdx.x; idx < F * F + F; idx += 256) dstp[idx] = ls[idx];
}

// ---------------- F=64 stats: LDS-tiled rank-1 accumulation ----------------
__global__ __launch_bounds__(256) void k_ata64(const float* __restrict__ A,
                                               float* __restrict__ part) {
  __shared__ float lA[64 * 64];   // [node][ch]
  __shared__ float lcs[64];
  int tid = threadIdx.x;
  int tx = tid & 15, ty = tid >> 4;
  float acc[4][4];
#pragma unroll
  for (int i = 0; i < 4; ++i)
#pragma unroll
    for (int j = 0; j < 4; ++j) acc[i][j] = 0.f;
  float cs0 = 0.f, cs1 = 0.f, cs2 = 0.f, cs3 = 0.f;
  if (tid < 64) lcs[tid] = 0.f;
  const float4* A4 = (const float4*)A;
  for (int tile = blockIdx.x; tile < NTILE; tile += gridDim.x) {
    int nbase = tile * 64;
    __syncthreads();   // protect lA from previous iteration's readers
#pragma unroll
    for (int k = 0; k < 4; ++k) {
      int node = ty + k * 16;
      int gn = nbase + node;
      float4 v = (gn < NN) ? A4[(size_t)gn * 16 + tx]
                           : make_float4(0.f, 0.f, 0.f, 0.f);
      *(float4*)&lA[node * 64 + tx * 4] = v;
      cs0 += v.x; cs1 += v.y; cs2 += v.z; cs3 += v.w;
    }
    __syncthreads();
#pragma unroll 4
    for (int node = 0; node < 64; ++node) {
      float4 rv = *(const float4*)&lA[node * 64 + ty * 4];
      float4 cv = *(const float4*)&lA[node * 64 + tx * 4];
      acc[0][0] += rv.x * cv.x; acc[0][1] += rv.x * cv.y;
      acc[0][2] += rv.x * cv.z; acc[0][3] += rv.x * cv.w;
      acc[1][0] += rv.y * cv.x; acc[1][1] += rv.y * cv.y;
      acc[1][2] += rv.y * cv.z; acc[1][3] += rv.y * cv.w;
      acc[2][0] += rv.z * cv.x; acc[2][1] += rv.z * cv.y;
      acc[2][2] += rv.z * cv.z; acc[2][3] += rv.z * cv.w;
      acc[3][0] += rv.w * cv.x; acc[3][1] += rv.w * cv.y;
      acc[3][2] += rv.w * cv.z; acc[3][3] += rv.w * cv.w;
    }
  }
  __syncthreads();
  atomicAdd(&lcs[tx * 4 + 0], cs0);
  atomicAdd(&lcs[tx * 4 + 1], cs1);
  atomicAdd(&lcs[tx * 4 + 2], cs2);
  atomicAdd(&lcs[tx * 4 + 3], cs3);
  float* dstp = part + (size_t)blockIdx.x * 4160;
#pragma unroll
  for (int i = 0; i < 4; ++i)
#pragma unroll
    for (int j = 0; j < 4; ++j)
      dstp[(ty * 4 + i) * 64 + tx * 4 + j] = acc[i][j];
  __syncthreads();
  if (tid < 64) dstp[4096 + tid] = lcs[tid];
}

// ---------------- reduce partials: block-per-index tree ----------------
__global__ void k_redB(const float* __restrict__ part, float* __restrict__ out,
                       int stride, int ngrid) {
  __shared__ float buf[256];
  int i = blockIdx.x;
  float s = 0.f;
  for (int g = threadIdx.x; g < ngrid; g += 256) s += part[(size_t)g * stride + i];
  buf[threadIdx.x] = s;
  __syncthreads();
  for (int off = 128; off; off >>= 1) {
    if (threadIdx.x < off) buf[threadIdx.x] += buf[threadIdx.x + off];
    __syncthreads();
  }
  if (threadIdx.x == 0) out[i] = buf[0];
}

// ---------------- BN params from covariance ----------------
template<int FIN, int FMID>
__global__ void k_bnprep(const float* __restrict__ S, const float* __restrict__ cs,
                         const float* __restrict__ Wm, const float* __restrict__ bm,
                         const float* __restrict__ gamma, const float* __restrict__ beta,
                         float* __restrict__ ab) {
  int j = blockIdx.x;
  int lane = threadIdx.x;
  bool act = (FIN == 64) || (lane < FIN);
  float wj = act ? Wm[lane * FMID + j] : 0.f;
  float mb = act ? cs[lane] * (1.f / NN) : 0.f;
  float t = mb * wj;
#pragma unroll
  for (int off = 32; off; off >>= 1) t += __shfl_xor(t, off, 64);
  float mulin = t;
  float acc = 0.f;
  for (int c = 0; c < FIN; ++c) {
    float sv = act ? S[c * FIN + lane] : 0.f;
    float p = sv * wj;
#pragma unroll
    for (int off = 32; off; off >>= 1) p += __shfl_xor(p, off, 64);
    acc += p * __shfl(wj, c, 64);
  }
  if (lane == 0) {
    float var = acc * (1.f / NN) - mulin * mulin;
    float rstd = rsqrtf(fmaxf(var, 0.f) + 1e-5f);
    float sc = rstd * gamma[j];
    ab[j] = sc;
    ab[FMID + j] = beta[j] - mulin * sc;
  }
}

// ---------------- fused GEMM1 + BN + relu + GEMM2 + residual (+ bf16 relu copy) ----
// FMID==128: mid activations stored as packed bf16 pairs -> LDS 33.3KB, 4 blocks/CU.
template<int FIN, int FMID, int FOUT, int MODE>  // MODE 0: H=relu(out); 1: H+=out
__global__ __launch_bounds__(256) void k_layer(const float* __restrict__ A,
                                               const float* __restrict__ Wm,
                                               const float* __restrict__ ab,
                                               const float* __restrict__ W2,
                                               const float* __restrict__ b2,
                                               float* __restrict__ H,
                                               unsigned short* __restrict__ XB) {
  constexpr bool PK = (FMID == 128);
  constexpr int SM = FMID + 1;
  constexpr int MW = FMID / 4;
  constexpr int OW = FOUT / 4;
  __shared__ float lA[FIN * 65];             // transposed: lA[c][node], stride 65
  __shared__ unsigned lHp[PK ? 64 * 65 : 1]; // packed bf16 pairs [node][pair], stride 65
  __shared__ float lH[PK ? 1 : 64 * SM];
  int tid = threadIdx.x;
  int lane = tid & 63;
  int w = __builtin_amdgcn_readfirstlane(tid >> 6);
  int nbase = blockIdx.x * 64;
  if (FIN == 64) {
    const float4* A4 = (const float4*)A;
    for (int e = tid; e < 64 * 16; e += 256) {
      int node = e >> 4;
      int c4 = (e & 15) << 2;
      int gn = nbase + node;
      float4 v = (gn < NN) ? A4[(size_t)gn * 16 + (e & 15)] : make_float4(0.f, 0.f, 0.f, 0.f);
      lA[(c4 + 0) * 65 + node] = v.x;
      lA[(c4 + 1) * 65 + node] = v.y;
      lA[(c4 + 2) * 65 + node] = v.z;
      lA[(c4 + 3) * 65 + node] = v.w;
    }
  } else {
    for (int e = tid; e < 64 * FIN; e += 256) {
      int node = e / FIN, c = e - node * FIN;
      int gn = nbase + node;
      lA[c * 65 + node] = (gn < NN) ? A[(size_t)gn * FIN + c] : 0.f;
    }
  }
  __syncthreads();
  // phase 1: mid = A @ Wm (this wave's MW channels) + BN affine + relu -> LDS
  float acc[MW];
#pragma unroll
  for (int j = 0; j < MW; ++j) acc[j] = 0.f;
#pragma unroll 4
  for (int c = 0; c < FIN; ++c) {
    float a = lA[c * 65 + lane];
#pragma unroll
    for (int j = 0; j < MW; ++j) acc[j] += a * Wm[c * FMID + w * MW + j];
  }
  if constexpr (PK) {
#pragma unroll
    for (int j = 0; j < MW; j += 2) {
      float v0 = fmaxf(acc[j] * ab[w * MW + j] + ab[FMID + w * MW + j], 0.f);
      float v1 = fmaxf(acc[j + 1] * ab[w * MW + j + 1] + ab[FMID + w * MW + j + 1], 0.f);
      lHp[lane * 65 + (w * MW + j) / 2] =
          (unsigned)f2b(v0) | ((unsigned)f2b(v1) << 16);
    }
  } else {
#pragma unroll
    for (int j = 0; j < MW; ++j) {
      float sc = ab[w * MW + j];
      float sh = ab[FMID + w * MW + j];
      lH[lane * SM + w * MW + j] = fmaxf(acc[j] * sc + sh, 0.f);
    }
  }
  __syncthreads();
  // phase 2: out = h1 @ W2 + b2 (this wave's OW channels)
  float acc2[OW];
#pragma unroll
  for (int j = 0; j < OW; ++j) acc2[j] = b2[w * OW + j];
  if constexpr (PK) {
#pragma unroll 4
    for (int c2 = 0; c2 < FMID / 2; ++c2) {
      unsigned u = lHp[lane * 65 + c2];
      float lo = b2f((unsigned short)(u & 0xffff));
      float hi = b2f((unsigned short)(u >> 16));
#pragma unroll
      for (int j = 0; j < OW; ++j) {
        acc2[j] += lo * W2[(2 * c2) * FOUT + w * OW + j];
        acc2[j] += hi * W2[(2 * c2 + 1) * FOUT + w * OW + j];
      }
    }
  } else {
#pragma unroll 4
    for (int c = 0; c < FMID; ++c) {
      float hv = lH[lane * SM + c];
#pragma unroll
      for (int j = 0; j < OW; ++j) acc2[j] += hv * W2[c * FOUT + w * OW + j];
    }
  }
  int node = nbase + lane;
  if (node < NN) {
    size_t base = (size_t)node * FOUT + w * OW;
    if (MODE == 0) {
#pragma unroll
      for (int j = 0; j < OW; ++j) {
        float hn = fmaxf(acc2[j], 0.f);
        H[base + j] = hn;
        XB[base + j] = f2b(hn);           // already >= 0
      }
    } else {
#pragma unroll
      for (int j = 0; j < OW; ++j) {
        float hn = H[base + j] + acc2[j];
        H[base + j] = hn;
        XB[base + j] = f2b(fmaxf(hn, 0.f));
      }
    }
  }
}

// ---------------- pool: segmented register max (batch is sorted) ----------------
__global__ __launch_bounds__(256) void k_pool(const float* __restrict__ h,
                                              const int* __restrict__ batch,
                                              unsigned* __restrict__ gmax) {
  int wgid = blockIdx.x * 4 + (threadIdx.x >> 6);
  int lane = threadIdx.x & 63;
  const int per = (NN + POOL_WAVES - 1) / POOL_WAVES;  // 49
  int n0 = wgid * per;
  int n1 = min(n0 + per, NN);
  if (n0 >= NN) return;
  int g = batch[n0];
  float m = -INFINITY;
  for (int node = n0; node < n1; ++node) {
    int b = batch[node];
    if (b != g) {
      atomicMax(&gmax[(g << 6) + lane], fmap(m));
      m = -INFINITY;
      g = b;
    }
    m = fmaxf(m, h[(size_t)node * 64 + lane]);
  }
  atomicMax(&gmax[(g << 6) + lane], fmap(m));
}

__global__ void k_final(const unsigned* __restrict__ gmax, const float* __restrict__ w1,
                        const float* __restrict__ b1, const float* __restrict__ w2,
                        const float* __restrict__ b2, float* __restrict__ out) {
  int b = blockIdx.x;
  __shared__ float g[64], hid[64];
  int t = threadIdx.x;
  if (t < 64) {
    float v = funmap(gmax[b * 64 + t]);
    if (v == -INFINITY) v = 0.f;
    g[t] = v;
  }
  __syncthreads();
  if (t < 64) {
    float acc = b1[t];
    for (int c = 0; c < 64; ++c) acc += g[c] * w1[c * 64 + t];
    hid[t] = fmaxf(acc, 0.f);
  }
  __syncthreads();
  if (t < 80) {
    float acc = b2[t];
    for (int c = 0; c < 64; ++c) acc += hid[c] * w2[c * 80 + t];
    out[b * 80 + t] = acc;
  }
}

extern "C" void kernel_launch(void* const* d_in, const int* in_sizes, int n_in,
                              void* d_out, int out_size, void* d_ws, size_t ws_size,
                              hipStream_t stream) {
  const float* x       = (const float*)d_in[0];
  const int*   ei      = (const int*)d_in[1];
  const int*   batch   = (const int*)d_in[2];
  const float* cin_w1  = (const float*)d_in[3];
  const float* cin_b1  = (const float*)d_in[4];
  const float* cin_g1  = (const float*)d_in[5];
  const float* cin_be1 = (const float*)d_in[6];
  const float* cin_w2  = (const float*)d_in[7];
  const float* cin_b2  = (const float*)d_in[8];
  const float* L_w1    = (const float*)d_in[9];
  const float* L_b1    = (const float*)d_in[10];
  const float* L_g1    = (const float*)d_in[11];
  const float* L_be1   = (const float*)d_in[12];
  const float* L_w2    = (const float*)d_in[13];
  const float* L_b2    = (const float*)d_in[14];
  const float* mlp_w1  = (const float*)d_in[15];
  const float* mlp_b1  = (const float*)d_in[16];
  const float* mlp_w2  = (const float*)d_in[17];
  const float* mlp_b2  = (const float*)d_in[18];

  char* ws = (char*)d_ws;
  size_t off = 0;
  auto alloc = [&](size_t bytes) -> void* {
    void* p = ws + off;
    off = (off + bytes + 255) & ~(size_t)255;
    return p;
  };
  float*          A       = (float*)alloc((size_t)NN * 64 * 4);
  float*          h       = (float*)alloc((size_t)NN * 64 * 4);
  unsigned short* xb      = (unsigned short*)alloc((size_t)NN * 64 * 2);
  int*            rowptr  = (int*)alloc((size_t)(NN + 1) * 4);
  int*            cursor  = (int*)alloc((size_t)NN * 4);
  int*            adjsrc  = (int*)alloc((size_t)EE * 4);
  int*            partial = (int*)alloc(NSCAN * 4);
  int*            poffs   = (int*)alloc(128 * 4);
  int*            bcur    = (int*)alloc(SC_CLS * 4);
  float*          part    = (float*)alloc((size_t)AG6 * 4160 * 4);  // also ebuf (12.8MB)
  float*          Sfin    = (float*)alloc((size_t)4 * 4160 * 4);
  float*          ab      = (float*)alloc((size_t)4 * 256 * 4);
  unsigned*       gmax    = (unsigned*)alloc((size_t)BB * 64 * 4);
  int2*           ebuf    = (int2*)part;   // reused before any ata kernel runs
  (void)ws_size; (void)in_sizes; (void)n_in; (void)out_size;

  const int* srcp = ei;
  const int* dstp = ei + EE;

  // CSR build (two-phase bucketed scatter)
  hipMemsetAsync(cursor, 0, (size_t)NN * 4, stream);
  k_hist<<<(EE + 255) / 256, 256, 0, stream>>>(dstp, cursor);
  k_scan1<<<NSCAN, 1024, 0, stream>>>(cursor, rowptr, partial);
  k_scan2<<<1, 128, 0, stream>>>(partial, poffs, gmax);
  k_scan3<<<NSCAN, 1024, 0, stream>>>(rowptr, poffs, cursor, bcur);
  k_bucket<<<BK_GRID, 256, 0, stream>>>(srcp, dstp, bcur, ebuf);
  k_scatter2<<<SC_GRID, 256, 0, stream>>>(ebuf, rowptr, cursor, adjsrc);

  const int NB64 = (NN + 63) / 64;  // 1563

  // Layer 0: x[N,6] -> h[N,64] (+ xb = bf16 relu copy)
  {
    float* S = Sfin;
    float* cs = S + 6 * 6;
    float* ab0 = ab;
    k_agg0<<<NN / 4, 256, 0, stream>>>(x, rowptr, adjsrc, A);
    k_ata6<<<AG6, 256, 0, stream>>>(A, part);
    k_redB<<<42, 256, 0, stream>>>(part, S, 42, AG6);
    k_bnprep<6, 12><<<12, 64, 0, stream>>>(S, cs, cin_w1, cin_b1, cin_g1, cin_be1, ab0);
    k_layer<6, 12, 64, 0><<<NB64, 256, 0, stream>>>(A, cin_w1, ab0, cin_w2, cin_b2, h, xb);
  }

  // Layers 1..3: h += MLP(BN(agg(relu(h)) @ W1)) @ W2
  for (int i = 0; i < 3; ++i) {
    float* S = Sfin + (size_t)(i + 1) * 4160;
    float* cs = S + 64 * 64;
    float* abi = ab + (size_t)(i + 1) * 256;
    k_aggb<<<NN / 4, 256, 0, stream>>>(xb, h, rowptr, adjsrc, A);
    k_ata64<<<AG64, 256, 0, stream>>>(A, part);
    k_redB<<<4160, 256, 0, stream>>>(part, S, 4160, AG64);
    k_bnprep<64, 128><<<128, 64, 0, stream>>>(S, cs, L_w1 + (size_t)i * 64 * 128,
                                              L_b1 + i * 128, L_g1 + i * 128,
                                              L_be1 + i * 128, abi);
    k_layer<64, 128, 64, 1><<<NB64, 256, 0, stream>>>(A, L_w1 + (size_t)i * 64 * 128, abi,
                                                      L_w2 + (size_t)i * 128 * 64,
                                                      L_b2 + i * 64, h, xb);
  }

  // Global max pool + final MLP
  k_pool<<<POOL_BLK, 256, 0, stream>>>(h, batch, gmax);
  k_final<<<BB, 128, 0, stream>>>(gmax, mlp_w1, mlp_b1, mlp_w2, mlp_b2, (float*)d_out);
}

// Round 11
// 672.070 us; speedup vs baseline: 1.1259x; 1.1126x over previous
//
#include <hip/hip_runtime.h>

#define NN 100000
#define EE 1600000
#define BB 64
#define NSCAN 98      // ceil(NN/1024)
#define AG6 1024      // grid for F=6 stats
#define AG64 640      // grid for F=64 tiled ata
#define NTILE 1563    // ceil(NN/64)
#define POOL_BLK 512
#define POOL_WAVES (POOL_BLK * 4)

__device__ __forceinline__ unsigned fmap(float f) {
  unsigned u = __float_as_uint(f);
  return (u & 0x80000000u) ? ~u : (u | 0x80000000u);
}
__device__ __forceinline__ float funmap(unsigned m) {
  unsigned u = (m & 0x80000000u) ? (m ^ 0x80000000u) : ~m;
  return __uint_as_float(u);
}
__device__ __forceinline__ unsigned short f2b(float f) {
  unsigned u = __float_as_uint(f);
  unsigned r = (u + 0x7FFFu + ((u >> 16) & 1u)) >> 16;
  return (unsigned short)r;
}
__device__ __forceinline__ float b2f(unsigned short s) {
  return __uint_as_float(((unsigned)s) << 16);
}

// ---------------- CSR build (by dst) ----------------
// hist also records each edge's arrival rank within its dst (free from the atomic).
__global__ void k_hist(const int* __restrict__ dst, int* __restrict__ counts,
                       int* __restrict__ rank) {
  int i = blockIdx.x * blockDim.x + threadIdx.x;
  if (i < EE) rank[i] = atomicAdd(&counts[dst[i]], 1);
}

__global__ void k_scan1(const int* __restrict__ counts, int* __restrict__ rowptr,
                        int* __restrict__ partials) {
  __shared__ int buf[1024];
  int i = blockIdx.x * 1024 + threadIdx.x;
  int v = (i < NN) ? counts[i] : 0;
  buf[threadIdx.x] = v;
  __syncthreads();
  for (int off = 1; off < 1024; off <<= 1) {
    int t = (threadIdx.x >= off) ? buf[threadIdx.x - off] : 0;
    __syncthreads();
    buf[threadIdx.x] += t;
    __syncthreads();
  }
  int incl = buf[threadIdx.x];
  if (i < NN) rowptr[i] = incl - v;
  if (threadIdx.x == 1023) partials[blockIdx.x] = incl;
}

__global__ void k_scan2(const int* __restrict__ partials, int* __restrict__ poffs,
                        unsigned* __restrict__ gmax) {
  __shared__ int buf[128];
  int t = threadIdx.x;
  int v = (t < NSCAN) ? partials[t] : 0;
  buf[t] = v;
  __syncthreads();
  for (int off = 1; off < 128; off <<= 1) {
    int u = (t >= off) ? buf[t - off] : 0;
    __syncthreads();
    buf[t] += u;
    __syncthreads();
  }
  poffs[t] = buf[t] - v;
  for (int i = t; i < BB * 64; i += 128) gmax[i] = 0x007FFFFFu;  // fmap(-inf)
}

__global__ void k_scan3(int* __restrict__ rowptr, const int* __restrict__ poffs) {
  int i = blockIdx.x * 1024 + threadIdx.x;
  if (i < NN) rowptr[i] += poffs[blockIdx.x];
  if (i == 0) rowptr[NN] = EE;
}

// atomic-free placement: pos = rowptr[dst] + rank. Plain stores queue to the
// write-BW limit instead of serializing on atomic round-trips.
__global__ __launch_bounds__(256) void k_place(const int* __restrict__ src,
                                               const int* __restrict__ dst,
                                               const int* __restrict__ rank,
                                               const int* __restrict__ rowptr,
                                               int* __restrict__ adjsrc) {
  int i = blockIdx.x * blockDim.x + threadIdx.x;
  if (i < EE) adjsrc[rowptr[dst[i]] + rank[i]] = src[i];
}

// ---------------- layer-0 aggregation: f32 gather, F=6 ----------------
__global__ __launch_bounds__(256) void k_agg0(const float* __restrict__ xin,
                                              const int* __restrict__ rowptr,
                                              const int* __restrict__ adjsrc,
                                              float* __restrict__ out) {
  int w = __builtin_amdgcn_readfirstlane(threadIdx.x >> 6);
  int lane = threadIdx.x & 63;
  int wid = blockIdx.x * 4 + w;
  if (wid >= NN) return;
  int s = rowptr[wid], e = rowptr[wid + 1];
  bool act = lane < 6;
  float den = 0.f, num = 0.f;
  int i = s;
  for (; i + 3 < e; i += 4) {
    int n0 = adjsrc[i], n1 = adjsrc[i + 1], n2 = adjsrc[i + 2], n3 = adjsrc[i + 3];
    float v0 = act ? xin[(size_t)n0 * 6 + lane] : 0.f;
    float v1 = act ? xin[(size_t)n1 * 6 + lane] : 0.f;
    float v2 = act ? xin[(size_t)n2 * 6 + lane] : 0.f;
    float v3 = act ? xin[(size_t)n3 * 6 + lane] : 0.f;
    float m0 = fminf(fmaxf(v0, 0.f) + 1e-7f, 80.f);
    float m1 = fminf(fmaxf(v1, 0.f) + 1e-7f, 80.f);
    float m2 = fminf(fmaxf(v2, 0.f) + 1e-7f, 80.f);
    float m3 = fminf(fmaxf(v3, 0.f) + 1e-7f, 80.f);
    float e0 = __expf(m0), e1 = __expf(m1), e2 = __expf(m2), e3 = __expf(m3);
    den += (e0 + e1) + (e2 + e3);
    num += (m0 * e0 + m1 * e1) + (m2 * e2 + m3 * e3);
  }
  for (; i < e; ++i) {
    int n0 = adjsrc[i];
    float v0 = act ? xin[(size_t)n0 * 6 + lane] : 0.f;
    float m0 = fminf(fmaxf(v0, 0.f) + 1e-7f, 80.f);
    float e0 = __expf(m0);
    den += e0;
    num += m0 * e0;
  }
  if (act) {
    float xr = xin[(size_t)wid * 6 + lane];
    out[(size_t)wid * 6 + lane] = num / (den + 1e-16f) + xr;
  }
}

// ---------------- layers 1-3 aggregation: bf16 gather, f32 residual ----------------
__global__ __launch_bounds__(256) void k_aggb(const unsigned short* __restrict__ xb,
                                              const float* __restrict__ h,
                                              const int* __restrict__ rowptr,
                                              const int* __restrict__ adjsrc,
                                              float* __restrict__ out) {
  int w = __builtin_amdgcn_readfirstlane(threadIdx.x >> 6);
  int lane = threadIdx.x & 63;
  int wid = blockIdx.x * 4 + w;
  if (wid >= NN) return;
  int s = rowptr[wid], e = rowptr[wid + 1];
  float den = 0.f, num = 0.f;
  int i = s;
  for (; i + 3 < e; i += 4) {
    int n0 = adjsrc[i], n1 = adjsrc[i + 1], n2 = adjsrc[i + 2], n3 = adjsrc[i + 3];
    float v0 = b2f(xb[(size_t)n0 * 64 + lane]);
    float v1 = b2f(xb[(size_t)n1 * 64 + lane]);
    float v2 = b2f(xb[(size_t)n2 * 64 + lane]);
    float v3 = b2f(xb[(size_t)n3 * 64 + lane]);
    float m0 = fminf(v0 + 1e-7f, 80.f);   // xb already relu'd
    float m1 = fminf(v1 + 1e-7f, 80.f);
    float m2 = fminf(v2 + 1e-7f, 80.f);
    float m3 = fminf(v3 + 1e-7f, 80.f);
    float e0 = __expf(m0), e1 = __expf(m1), e2 = __expf(m2), e3 = __expf(m3);
    den += (e0 + e1) + (e2 + e3);
    num += (m0 * e0 + m1 * e1) + (m2 * e2 + m3 * e3);
  }
  for (; i < e; ++i) {
    int n0 = adjsrc[i];
    float v0 = b2f(xb[(size_t)n0 * 64 + lane]);
    float m0 = fminf(v0 + 1e-7f, 80.f);
    float e0 = __expf(m0);
    den += e0;
    num += m0 * e0;
  }
  float res = fmaxf(h[(size_t)wid * 64 + lane], 0.f);
  out[(size_t)wid * 64 + lane] = num / (den + 1e-16f) + res;
}

// ---------------- F=6 stats: shfl outer product (cheap) ----------------
__global__ __launch_bounds__(256) void k_ata6(const float* __restrict__ A,
                                              float* __restrict__ part) {
  constexpr int F = 6;
  int lane = threadIdx.x & 63;
  int w = __builtin_amdgcn_readfirstlane(threadIdx.x >> 6);
  bool act = lane < F;
  float Sloc[F];
#pragma unroll
  for (int c = 0; c < F; ++c) Sloc[c] = 0.f;
  float csloc = 0.f;
  int NW = gridDim.x * 4;
  for (int node = blockIdx.x * 4 + w; node < NN; node += NW) {
    float a = act ? A[(size_t)node * F + lane] : 0.f;
    csloc += a;
#pragma unroll
    for (int c = 0; c < F; ++c) {
      float ac = __shfl(a, c, 64);
      Sloc[c] += ac * a;
    }
  }
  __shared__ float ls[F * F + F];
  for (int idx = threadIdx.x; idx < F * F + F; idx += 256) ls[idx] = 0.f;
  __syncthreads();
  if (act) {
#pragma unroll
    for (int c = 0; c < F; ++c) atomicAdd(&ls[c * F + lane], Sloc[c]);
    atomicAdd(&ls[F * F + lane], csloc);
  }
  __syncthreads();
  float* dstp = part + (size_t)blockIdx.x * (F * F + F);
  for (int idx = threadIdx.x; idx < F * F + F; idx += 256) dstp[idx] = ls[idx];
}

// ---------------- F=64 stats: LDS-tiled rank-1 accumulation ----------------
__global__ __launch_bounds__(256) void k_ata64(const float* __restrict__ A,
                                               float* __restrict__ part) {
  __shared__ float lA[64 * 64];   // [node][ch]
  __shared__ float lcs[64];
  int tid = threadIdx.x;
  int tx = tid & 15, ty = tid >> 4;
  float acc[4][4];
#pragma unroll
  for (int i = 0; i < 4; ++i)
#pragma unroll
    for (int j = 0; j < 4; ++j) acc[i][j] = 0.f;
  float cs0 = 0.f, cs1 = 0.f, cs2 = 0.f, cs3 = 0.f;
  if (tid < 64) lcs[tid] = 0.f;
  const float4* A4 = (const float4*)A;
  for (int tile = blockIdx.x; tile < NTILE; tile += gridDim.x) {
    int nbase = tile * 64;
    __syncthreads();   // protect lA from previous iteration's readers
#pragma unroll
    for (int k = 0; k < 4; ++k) {
      int node = ty + k * 16;
      int gn = nbase + node;
      float4 v = (gn < NN) ? A4[(size_t)gn * 16 + tx]
                           : make_float4(0.f, 0.f, 0.f, 0.f);
      *(float4*)&lA[node * 64 + tx * 4] = v;
      cs0 += v.x; cs1 += v.y; cs2 += v.z; cs3 += v.w;
    }
    __syncthreads();
#pragma unroll 4
    for (int node = 0; node < 64; ++node) {
      float4 rv = *(const float4*)&lA[node * 64 + ty * 4];
      float4 cv = *(const float4*)&lA[node * 64 + tx * 4];
      acc[0][0] += rv.x * cv.x; acc[0][1] += rv.x * cv.y;
      acc[0][2] += rv.x * cv.z; acc[0][3] += rv.x * cv.w;
      acc[1][0] += rv.y * cv.x; acc[1][1] += rv.y * cv.y;
      acc[1][2] += rv.y * cv.z; acc[1][3] += rv.y * cv.w;
      acc[2][0] += rv.z * cv.x; acc[2][1] += rv.z * cv.y;
      acc[2][2] += rv.z * cv.z; acc[2][3] += rv.z * cv.w;
      acc[3][0] += rv.w * cv.x; acc[3][1] += rv.w * cv.y;
      acc[3][2] += rv.w * cv.z; acc[3][3] += rv.w * cv.w;
    }
  }
  __syncthreads();
  atomicAdd(&lcs[tx * 4 + 0], cs0);
  atomicAdd(&lcs[tx * 4 + 1], cs1);
  atomicAdd(&lcs[tx * 4 + 2], cs2);
  atomicAdd(&lcs[tx * 4 + 3], cs3);
  float* dstp = part + (size_t)blockIdx.x * 4160;
#pragma unroll
  for (int i = 0; i < 4; ++i)
#pragma unroll
    for (int j = 0; j < 4; ++j)
      dstp[(ty * 4 + i) * 64 + tx * 4 + j] = acc[i][j];
  __syncthreads();
  if (tid < 64) dstp[4096 + tid] = lcs[tid];
}

// ---------------- reduce partials: block-per-index tree ----------------
__global__ void k_redB(const float* __restrict__ part, float* __restrict__ out,
                       int stride, int ngrid) {
  __shared__ float buf[256];
  int i = blockIdx.x;
  float s = 0.f;
  for (int g = threadIdx.x; g < ngrid; g += 256) s += part[(size_t)g * stride + i];
  buf[threadIdx.x] = s;
  __syncthreads();
  for (int off = 128; off; off >>= 1) {
    if (threadIdx.x < off) buf[threadIdx.x] += buf[threadIdx.x + off];
    __syncthreads();
  }
  if (threadIdx.x == 0) out[i] = buf[0];
}

// ---------------- BN params from covariance ----------------
template<int FIN, int FMID>
__global__ void k_bnprep(const float* __restrict__ S, const float* __restrict__ cs,
                         const float* __restrict__ Wm, const float* __restrict__ bm,
                         const float* __restrict__ gamma, const float* __restrict__ beta,
                         float* __restrict__ ab) {
  int j = blockIdx.x;
  int lane = threadIdx.x;
  bool act = (FIN == 64) || (lane < FIN);
  float wj = act ? Wm[lane * FMID + j] : 0.f;
  float mb = act ? cs[lane] * (1.f / NN) : 0.f;
  float t = mb * wj;
#pragma unroll
  for (int off = 32; off; off >>= 1) t += __shfl_xor(t, off, 64);
  float mulin = t;
  float acc = 0.f;
  for (int c = 0; c < FIN; ++c) {
    float sv = act ? S[c * FIN + lane] : 0.f;
    float p = sv * wj;
#pragma unroll
    for (int off = 32; off; off >>= 1) p += __shfl_xor(p, off, 64);
    acc += p * __shfl(wj, c, 64);
  }
  if (lane == 0) {
    float var = acc * (1.f / NN) - mulin * mulin;
    float rstd = rsqrtf(fmaxf(var, 0.f) + 1e-5f);
    float sc = rstd * gamma[j];
    ab[j] = sc;
    ab[FMID + j] = beta[j] - mulin * sc;
  }
}

// ---------------- fused GEMM1 + BN + relu + GEMM2 + residual (+ bf16 relu copy) ----
// FMID==128: mid activations stored as packed bf16 pairs -> LDS 33.3KB, 4 blocks/CU.
template<int FIN, int FMID, int FOUT, int MODE>  // MODE 0: H=relu(out); 1: H+=out
__global__ __launch_bounds__(256) void k_layer(const float* __restrict__ A,
                                               const float* __restrict__ Wm,
                                               const float* __restrict__ ab,
                                               const float* __restrict__ W2,
                                               const float* __restrict__ b2,
                                               float* __restrict__ H,
                                               unsigned short* __restrict__ XB) {
  constexpr bool PK = (FMID == 128);
  constexpr int SM = FMID + 1;
  constexpr int MW = FMID / 4;
  constexpr int OW = FOUT / 4;
  __shared__ float lA[FIN * 65];             // transposed: lA[c][node], stride 65
  __shared__ unsigned lHp[PK ? 64 * 65 : 1]; // packed bf16 pairs [node][pair], stride 65
  __shared__ float lH[PK ? 1 : 64 * SM];
  int tid = threadIdx.x;
  int lane = tid & 63;
  int w = __builtin_amdgcn_readfirstlane(tid >> 6);
  int nbase = blockIdx.x * 64;
  if (FIN == 64) {
    const float4* A4 = (const float4*)A;
    for (int e = tid; e < 64 * 16; e += 256) {
      int node = e >> 4;
      int c4 = (e & 15) << 2;
      int gn = nbase + node;
      float4 v = (gn < NN) ? A4[(size_t)gn * 16 + (e & 15)] : make_float4(0.f, 0.f, 0.f, 0.f);
      lA[(c4 + 0) * 65 + node] = v.x;
      lA[(c4 + 1) * 65 + node] = v.y;
      lA[(c4 + 2) * 65 + node] = v.z;
      lA[(c4 + 3) * 65 + node] = v.w;
    }
  } else {
    for (int e = tid; e < 64 * FIN; e += 256) {
      int node = e / FIN, c = e - node * FIN;
      int gn = nbase + node;
      lA[c * 65 + node] = (gn < NN) ? A[(size_t)gn * FIN + c] : 0.f;
    }
  }
  __syncthreads();
  // phase 1: mid = A @ Wm (this wave's MW channels) + BN affine + relu -> LDS
  float acc[MW];
#pragma unroll
  for (int j = 0; j < MW; ++j) acc[j] = 0.f;
#pragma unroll 4
  for (int c = 0; c < FIN; ++c) {
    float a = lA[c * 65 + lane];
#pragma unroll
    for (int j = 0; j < MW; ++j) acc[j] += a * Wm[c * FMID + w * MW + j];
  }
  if constexpr (PK) {
#pragma unroll
    for (int j = 0; j < MW; j += 2) {
      float v0 = fmaxf(acc[j] * ab[w * MW + j] + ab[FMID + w * MW + j], 0.f);
      float v1 = fmaxf(acc[j + 1] * ab[w * MW + j + 1] + ab[FMID + w * MW + j + 1], 0.f);
      lHp[lane * 65 + (w * MW + j) / 2] =
          (unsigned)f2b(v0) | ((unsigned)f2b(v1) << 16);
    }
  } else {
#pragma unroll
    for (int j = 0; j < MW; ++j) {
      float sc = ab[w * MW + j];
      float sh = ab[FMID + w * MW + j];
      lH[lane * SM + w * MW + j] = fmaxf(acc[j] * sc + sh, 0.f);
    }
  }
  __syncthreads();
  // phase 2: out = h1 @ W2 + b2 (this wave's OW channels)
  float acc2[OW];
#pragma unroll
  for (int j = 0; j < OW; ++j) acc2[j] = b2[w * OW + j];
  if constexpr (PK) {
#pragma unroll 4
    for (int c2 = 0; c2 < FMID / 2; ++c2) {
      unsigned u = lHp[lane * 65 + c2];
      float lo = b2f((unsigned short)(u & 0xffff));
      float hi = b2f((unsigned short)(u >> 16));
#pragma unroll
      for (int j = 0; j < OW; ++j) {
        acc2[j] += lo * W2[(2 * c2) * FOUT + w * OW + j];
        acc2[j] += hi * W2[(2 * c2 + 1) * FOUT + w * OW + j];
      }
    }
  } else {
#pragma unroll 4
    for (int c = 0; c < FMID; ++c) {
      float hv = lH[lane * SM + c];
#pragma unroll
      for (int j = 0; j < OW; ++j) acc2[j] += hv * W2[c * FOUT + w * OW + j];
    }
  }
  int node = nbase + lane;
  if (node < NN) {
    size_t base = (size_t)node * FOUT + w * OW;
    if (MODE == 0) {
#pragma unroll
      for (int j = 0; j < OW; ++j) {
        float hn = fmaxf(acc2[j], 0.f);
        H[base + j] = hn;
        XB[base + j] = f2b(hn);           // already >= 0
      }
    } else {
#pragma unroll
      for (int j = 0; j < OW; ++j) {
        float hn = H[base + j] + acc2[j];
        H[base + j] = hn;
        XB[base + j] = f2b(fmaxf(hn, 0.f));
      }
    }
  }
}

// ---------------- pool: segmented register max (batch is sorted) ----------------
__global__ __launch_bounds__(256) void k_pool(const float* __restrict__ h,
                                              const int* __restrict__ batch,
                                              unsigned* __restrict__ gmax) {
  int wgid = blockIdx.x * 4 + (threadIdx.x >> 6);
  int lane = threadIdx.x & 63;
  const int per = (NN + POOL_WAVES - 1) / POOL_WAVES;  // 49
  int n0 = wgid * per;
  int n1 = min(n0 + per, NN);
  if (n0 >= NN) return;
  int g = batch[n0];
  float m = -INFINITY;
  for (int node = n0; node < n1; ++node) {
    int b = batch[node];
    if (b != g) {
      atomicMax(&gmax[(g << 6) + lane], fmap(m));
      m = -INFINITY;
      g = b;
    }
    m = fmaxf(m, h[(size_t)node * 64 + lane]);
  }
  atomicMax(&gmax[(g << 6) + lane], fmap(m));
}

__global__ void k_final(const unsigned* __restrict__ gmax, const float* __restrict__ w1,
                        const float* __restrict__ b1, const float* __restrict__ w2,
                        const float* __restrict__ b2, float* __restrict__ out) {
  int b = blockIdx.x;
  __shared__ float g[64], hid[64];
  int t = threadIdx.x;
  if (t < 64) {
    float v = funmap(gmax[b * 64 + t]);
    if (v == -INFINITY) v = 0.f;
    g[t] = v;
  }
  __syncthreads();
  if (t < 64) {
    float acc = b1[t];
    for (int c = 0; c < 64; ++c) acc += g[c] * w1[c * 64 + t];
    hid[t] = fmaxf(acc, 0.f);
  }
  __syncthreads();
  if (t < 80) {
    float acc = b2[t];
    for (int c = 0; c < 64; ++c) acc += hid[c] * w2[c * 80 + t];
    out[b * 80 + t] = acc;
  }
}

extern "C" void kernel_launch(void* const* d_in, const int* in_sizes, int n_in,
                              void* d_out, int out_size, void* d_ws, size_t ws_size,
                              hipStream_t stream) {
  const float* x       = (const float*)d_in[0];
  const int*   ei      = (const int*)d_in[1];
  const int*   batch   = (const int*)d_in[2];
  const float* cin_w1  = (const float*)d_in[3];
  const float* cin_b1  = (const float*)d_in[4];
  const float* cin_g1  = (const float*)d_in[5];
  const float* cin_be1 = (const float*)d_in[6];
  const float* cin_w2  = (const float*)d_in[7];
  const float* cin_b2  = (const float*)d_in[8];
  const float* L_w1    = (const float*)d_in[9];
  const float* L_b1    = (const float*)d_in[10];
  const float* L_g1    = (const float*)d_in[11];
  const float* L_be1   = (const float*)d_in[12];
  const float* L_w2    = (const float*)d_in[13];
  const float* L_b2    = (const float*)d_in[14];
  const float* mlp_w1  = (const float*)d_in[15];
  const float* mlp_b1  = (const float*)d_in[16];
  const float* mlp_w2  = (const float*)d_in[17];
  const float* mlp_b2  = (const float*)d_in[18];

  char* ws = (char*)d_ws;
  size_t off = 0;
  auto alloc = [&](size_t bytes) -> void* {
    void* p = ws + off;
    off = (off + bytes + 255) & ~(size_t)255;
    return p;
  };
  float*          A       = (float*)alloc((size_t)NN * 64 * 4);
  float*          h       = (float*)alloc((size_t)NN * 64 * 4);
  unsigned short* xb      = (unsigned short*)alloc((size_t)NN * 64 * 2);
  int*            rowptr  = (int*)alloc((size_t)(NN + 1) * 4);
  int*            counts  = (int*)alloc((size_t)NN * 4);
  int*            rank    = (int*)alloc((size_t)EE * 4);
  int*            adjsrc  = (int*)alloc((size_t)EE * 4);
  int*            partial = (int*)alloc(NSCAN * 4);
  int*            poffs   = (int*)alloc(128 * 4);
  float*          part    = (float*)alloc((size_t)AG6 * 4160 * 4);
  float*          Sfin    = (float*)alloc((size_t)4 * 4160 * 4);
  float*          ab      = (float*)alloc((size_t)4 * 256 * 4);
  unsigned*       gmax    = (unsigned*)alloc((size_t)BB * 64 * 4);
  (void)ws_size; (void)in_sizes; (void)n_in; (void)out_size;

  const int* srcp = ei;
  const int* dstp = ei + EE;

  // CSR build: hist (emits ranks) -> scan -> atomic-free placement
  hipMemsetAsync(counts, 0, (size_t)NN * 4, stream);
  k_hist<<<(EE + 255) / 256, 256, 0, stream>>>(dstp, counts, rank);
  k_scan1<<<NSCAN, 1024, 0, stream>>>(counts, rowptr, partial);
  k_scan2<<<1, 128, 0, stream>>>(partial, poffs, gmax);
  k_scan3<<<NSCAN, 1024, 0, stream>>>(rowptr, poffs);
  k_place<<<(EE + 255) / 256, 256, 0, stream>>>(srcp, dstp, rank, rowptr, adjsrc);

  const int NB64 = (NN + 63) / 64;  // 1563

  // Layer 0: x[N,6] -> h[N,64] (+ xb = bf16 relu copy)
  {
    float* S = Sfin;
    float* cs = S + 6 * 6;
    float* ab0 = ab;
    k_agg0<<<NN / 4, 256, 0, stream>>>(x, rowptr, adjsrc, A);
    k_ata6<<<AG6, 256, 0, stream>>>(A, part);
    k_redB<<<42, 256, 0, stream>>>(part, S, 42, AG6);
    k_bnprep<6, 12><<<12, 64, 0, stream>>>(S, cs, cin_w1, cin_b1, cin_g1, cin_be1, ab0);
    k_layer<6, 12, 64, 0><<<NB64, 256, 0, stream>>>(A, cin_w1, ab0, cin_w2, cin_b2, h, xb);
  }

  // Layers 1..3: h += MLP(BN(agg(relu(h)) @ W1)) @ W2
  for (int i = 0; i < 3; ++i) {
    float* S = Sfin + (size_t)(i + 1) * 4160;
    float* cs = S + 64 * 64;
    float* abi = ab + (size_t)(i + 1) * 256;
    k_aggb<<<NN / 4, 256, 0, stream>>>(xb, h, rowptr, adjsrc, A);
    k_ata64<<<AG64, 256, 0, stream>>>(A, part);
    k_redB<<<4160, 256, 0, stream>>>(part, S, 4160, AG64);
    k_bnprep<64, 128><<<128, 64, 0, stream>>>(S, cs, L_w1 + (size_t)i * 64 * 128,
                                              L_b1 + i * 128, L_g1 + i * 128,
                                              L_be1 + i * 128, abi);
    k_layer<64, 128, 64, 1><<<NB64, 256, 0, stream>>>(A, L_w1 + (size_t)i * 64 * 128, abi,
                                                      L_w2 + (size_t)i * 128 * 64,
                                                      L_b2 + i * 64, h, xb);
  }

  // Global max pool + final MLP
  k_pool<<<POOL_BLK, 256, 0, stream>>>(h, batch, gmax);
  k_final<<<BB, 128, 0, stream>>>(gmax, mlp_w1, mlp_b1, mlp_w2, mlp_b2, (float*)d_out);
}